// Round 6
// baseline (498.319 us; speedup 1.0000x reference)
//
#include <hip/hip_runtime.h>
#include <stdint.h>

#define K_DIM 4096
#define N_DIM 4096
#define KB    32          // K / 128
#define QMAXF 127.0f

typedef int v4i __attribute__((ext_vector_type(4)));

__device__ __forceinline__ void async_copy16(void* lds, const void* gptr) {
    __builtin_amdgcn_global_load_lds(
        (__attribute__((address_space(1))) void*)gptr,
        (__attribute__((address_space(3))) void*)lds, 16, 0, 0);
}

// ---------------- activation quant: per (row, 128-block) ----------------
__global__ __launch_bounds__(256) void act_quant_kernel(
    const float* __restrict__ x, int8_t* __restrict__ xq,
    float* __restrict__ xs_t, int M)
{
    const int t = threadIdx.x;
    for (int m = blockIdx.x; m < M; m += gridDim.x) {
        const float* xrow = x + (size_t)m * K_DIM;
        int8_t* qrow = xq + (size_t)m * K_DIM;

#pragma unroll
        for (int p = 0; p < 4; ++p) {
            const int base = p * 1024 + t * 4;
            float4 v = *(const float4*)(xrow + base);
            float a = fmaxf(fmaxf(fabsf(v.x), fabsf(v.y)), fmaxf(fabsf(v.z), fabsf(v.w)));
#pragma unroll
            for (int off = 1; off < 32; off <<= 1)
                a = fmaxf(a, __shfl_xor(a, off, 64));
            const float s = fmaxf(a / QMAXF, 1e-12f);
            const float inv = 1.0f / s;
            float q0 = fminf(fmaxf(rintf(v.x * inv), -128.f), 127.f);
            float q1 = fminf(fmaxf(rintf(v.y * inv), -128.f), 127.f);
            float q2 = fminf(fmaxf(rintf(v.z * inv), -128.f), 127.f);
            float q3 = fminf(fmaxf(rintf(v.w * inv), -128.f), 127.f);
            char4 pk;
            pk.x = (char)(int)q0; pk.y = (char)(int)q1;
            pk.z = (char)(int)q2; pk.w = (char)(int)q3;
            *(char4*)(qrow + base) = pk;
            if ((t & 31) == 0) {
                const int g = base >> 7;
                xs_t[(size_t)g * M + m] = s;         // transposed [kb][M]
            }
        }
    }
}

// ---------------- weight quant: per 128x128 block ----------------
__global__ __launch_bounds__(256) void weight_quant_kernel(
    const float* __restrict__ w, int8_t* __restrict__ wq, float* __restrict__ ws)
{
    const int nb = blockIdx.x >> 5;
    const int kb = blockIdx.x & 31;
    const int t  = threadIdx.x;
    const int n0 = nb * 128, k0 = kb * 128;

    float4 vals[16];
    float a = 0.f;
#pragma unroll
    for (int ii = 0; ii < 16; ++ii) {
        const int e = ii * 1024 + t * 4;
        const int row = e >> 7, col = e & 127;
        float4 v = *(const float4*)(w + (size_t)(n0 + row) * K_DIM + k0 + col);
        vals[ii] = v;
        a = fmaxf(a, fmaxf(fmaxf(fabsf(v.x), fabsf(v.y)), fmaxf(fabsf(v.z), fabsf(v.w))));
    }
#pragma unroll
    for (int off = 1; off < 64; off <<= 1)
        a = fmaxf(a, __shfl_xor(a, off, 64));
    __shared__ float wred[4];
    if ((t & 63) == 0) wred[t >> 6] = a;
    __syncthreads();
    a = fmaxf(fmaxf(wred[0], wred[1]), fmaxf(wred[2], wred[3]));
    const float s = fmaxf(a / QMAXF, 1e-12f);
    const float inv = 1.0f / s;
    if (t == 0) ws[nb * KB + kb] = s;

#pragma unroll
    for (int ii = 0; ii < 16; ++ii) {
        const int e = ii * 1024 + t * 4;
        const int row = e >> 7, col = e & 127;
        float4 v = vals[ii];
        char4 pk;
        pk.x = (char)(int)fminf(fmaxf(rintf(v.x * inv), -128.f), 127.f);
        pk.y = (char)(int)fminf(fmaxf(rintf(v.y * inv), -128.f), 127.f);
        pk.z = (char)(int)fminf(fmaxf(rintf(v.z * inv), -128.f), 127.f);
        pk.w = (char)(int)fminf(fmaxf(rintf(v.w * inv), -128.f), 127.f);
        *(char4*)(wq + (size_t)(n0 + row) * K_DIM + k0 + col) = pk;
    }
}

// ---------------- int8 GEMM v6: 128x128, BK=64 ping-pong, 4 blocks/CU -------
// Model (r5 post-mortem): per 128^2-block-iter the LDS pipe moves 96KB
// (~857cyc @112B/cyc) vs matrix ~163cyc/SIMD -> LDS+drain dominate. Round-0
// (single-buf, 3 blk/CU, 2D grid) = 192us at ~48% LDS util; v5 lost a block
// (2 blk/CU) AND L2 locality (FETCH 187->283MB from the tile-slab XCD swizzle).
// v6: (a) BK=64 double-buffer -> LDS 33.75KB -> 4 blocks/CU (16 waves) for
// cross-block hiding; stages for step s+1 issue at top of step s, drained by
// the end-of-s syncthreads ~700cyc later (half the bytes per drain vs r0);
// (b) native 2D grid restored (round-0's bid%8 XCD round-robin keeps each
// XCD on the same 4 B-panels = 2MB, L2-resident; FETCH 187MB measured);
// (c) 4-chunk slot swizzle slot=r*4+((c^r^(r>>2))&3): within a 16-row frag
// read group, low-3 slot bits hit all 8 bank-groups -> conflict-free b128;
// (d) dequant per 64-K half with same per-kb scales (i32 partials < 2^24,
// cvt exact; one extra f32 rounding vs per-kb dequant).
// Register budget: facc 64 + a 16 + b 16 + transient xs/d/addr ~28 -> fits
// the 128-cap forced by launch_bounds(256,4) (round-0 reported 92 from a
// nominally-128 live set). Tripwire: WRITE_SIZE >> 131MB means spill.
__global__ __launch_bounds__(256, 4) void gemm_kernel(
    const int8_t* __restrict__ xq, const int8_t* __restrict__ wq,
    const float* __restrict__ xs_t, const float* __restrict__ ws,
    const float* __restrict__ bias, float* __restrict__ out, int M)
{
    __shared__ __align__(16) int8_t As[2][128 * 64];
    __shared__ __align__(16) int8_t Bs[2][128 * 64];
    __shared__ __align__(16) float  xs_lds[2][128];

    const int t    = threadIdx.x;
    const int lane = t & 63;
    const int wave = t >> 6;

    const int nbt = blockIdx.x;           // N/128 = 32  (2D grid, no swizzle)
    const int mbt = blockIdx.y;           // M/128 = 64
    const int n0  = nbt * 128;
    const int m0  = mbt * 128;

    const int wm    = (wave >> 1) * 64;
    const int wn    = (wave & 1) * 64;
    const int frow  = lane & 15;
    const int q     = lane >> 4;          // K-chunk (16B) index within 64-K half
    const int quad4 = q * 4;
    // swizzled chunk-slot for frag reads: constant across i (base row mult of 16)
    const int sw0   = ((q ^ frow ^ (frow >> 2)) & 3) * 16;
    const int wsrow = nbt * KB;

    // staging map: LDS slot s (0..511) holds global (r = s>>2,
    // c = ((s&3) ^ r ^ (r>>2)) & 3); byte offset within K-half = r*K_DIM + c*16
    int st_off[2];
#pragma unroll
    for (int it = 0; it < 2; ++it) {
        const int slot = it * 256 + t;
        const int r    = slot >> 2;
        const int c    = ((slot & 3) ^ r ^ (r >> 2)) & 3;
        st_off[it] = r * K_DIM + c * 16;
    }

    const int8_t* Abase = xq + (size_t)m0 * K_DIM;
    const int8_t* Bbase = wq + (size_t)n0 * K_DIM;

    float4 facc[4][4] = {};

    // ---- prologue: stage s=0 (kb0 half0) into buf 0 + xs(kb0) ----
#pragma unroll
    for (int it = 0; it < 2; ++it) {
        async_copy16(&As[0][(it * 256 + wave * 64) * 16], Abase + st_off[it]);
        async_copy16(&Bs[0][(it * 256 + wave * 64) * 16], Bbase + st_off[it]);
    }
    if (t < 32)
        async_copy16(&xs_lds[0][0], xs_t + m0 + t * 4);
    __syncthreads();

    for (int s = 0; s < 2 * KB; ++s) {
        const int cur = s & 1;
        const int nxt = cur ^ 1;
        const int kb  = s >> 1;

        // issue next-half stages FIRST (drained by end-of-step sync)
        if (s + 1 < 2 * KB) {
            const size_t kcol = (size_t)(s + 1) * 64;
#pragma unroll
            for (int it = 0; it < 2; ++it) {
                async_copy16(&As[nxt][(it * 256 + wave * 64) * 16], Abase + kcol + st_off[it]);
                async_copy16(&Bs[nxt][(it * 256 + wave * 64) * 16], Bbase + kcol + st_off[it]);
            }
            if ((s & 1) == 0 && t < 32)   // stage xs(kb+1) into opposite xs buf
                async_copy16(&xs_lds[(kb + 1) & 1][0],
                             xs_t + (size_t)(kb + 1) * M + m0 + t * 4);
        }

        const float wskb = ws[wsrow + kb];   // uniform -> scalar load

        // fragments from current buffer (row stride 64B, swizzled chunk slot)
        v4i a[4], b[4];
#pragma unroll
        for (int i = 0; i < 4; ++i)
            a[i] = *(const v4i*)&As[cur][(wm + i * 16 + frow) * 64 + sw0];
#pragma unroll
        for (int j = 0; j < 4; ++j)
            b[j] = *(const v4i*)&Bs[cur][(wn + j * 16 + frow) * 64 + sw0];

        // MFMA + per-half dequant (same per-kb scales), loosely scheduled
#pragma unroll
        for (int i = 0; i < 4; ++i) {
            const float4 xs4 = *(const float4*)&xs_lds[kb & 1][wm + i * 16 + quad4];
            const float s0 = xs4.x * wskb, s1 = xs4.y * wskb;
            const float s2 = xs4.z * wskb, s3 = xs4.w * wskb;
#pragma unroll
            for (int j = 0; j < 4; ++j) {
                v4i d = __builtin_amdgcn_mfma_i32_16x16x64_i8(a[i], b[j], (v4i){0, 0, 0, 0}, 0, 0, 0);
                facc[i][j].x += (float)d[0] * s0;
                facc[i][j].y += (float)d[1] * s1;
                facc[i][j].z += (float)d[2] * s2;
                facc[i][j].w += (float)d[3] * s3;
            }
        }

        // single boundary per half-step: drains this step's stage issues and
        // protects buffer `cur` from overwrite until all waves are done
        __syncthreads();
    }

    // epilogue: C/D layout col = lane&15, row = (lane>>4)*4 + reg
    float bj[4];
#pragma unroll
    for (int j = 0; j < 4; ++j) bj[j] = bias[n0 + wn + j * 16 + frow];
#pragma unroll
    for (int i = 0; i < 4; ++i) {
#pragma unroll
        for (int r = 0; r < 4; ++r) {
            const int row = m0 + wm + i * 16 + quad4 + r;
            float* orow = out + (size_t)row * N_DIM + n0 + wn + frow;
#pragma unroll
            for (int j = 0; j < 4; ++j)
                orow[j * 16] = ((const float*)&facc[i][j])[r] + bj[j];
        }
    }
}

extern "C" void kernel_launch(void* const* d_in, const int* in_sizes, int n_in,
                              void* d_out, int out_size, void* d_ws, size_t ws_size,
                              hipStream_t stream)
{
    const float* x    = (const float*)d_in[0];
    const float* w    = (const float*)d_in[1];
    const float* bias = (const float*)d_in[2];
    float* out = (float*)d_out;
    const int M = in_sizes[0] / K_DIM;   // 8192

    int8_t* xq  = (int8_t*)d_ws;                                 // M*K
    int8_t* wqp = xq + (size_t)M * K_DIM;                        // N*K
    float*  xst = (float*)(wqp + (size_t)N_DIM * K_DIM);         // KB*M  [kb][M]
    float*  wsp = xst + (size_t)KB * M;                          // (N/128)*KB

    act_quant_kernel<<<2048, 256, 0, stream>>>(x, xq, xst, M);
    weight_quant_kernel<<<(N_DIM / 128) * KB, 256, 0, stream>>>(w, wqp, wsp);
    gemm_kernel<<<dim3(N_DIM / 128, M / 128), 256, 0, stream>>>(
        xq, wqp, xst, wsp, bias, out, M);
}